// Round 17
// baseline (376.687 us; speedup 1.0000x reference)
//
#include <hip/hip_runtime.h>
#include <hip/hip_bf16.h>

#define N_NODES 50000
#define N_EDGES 800000
#define N_GRAPHS 64
#define HEADS 4
#define IN_CH 128
#define HID 64
#define F1 256  // HEADS*HID
#define OUT_CH 32
#define F2 128  // HEADS*OUT_CH
#define SCAN_B 256
#define SCAN_NB ((N_NODES + SCAN_B - 1) / SCAN_B)  // 196
#define GEMM_GRID ((N_NODES + 127) / 128)          // 391 (32 rows/wave)
#define COUNT_GRID ((N_EDGES + 255) / 256)         // 3125

typedef unsigned short ushortT;
typedef unsigned int uintT;
typedef short v8s __attribute__((ext_vector_type(8)));
typedef float v4f __attribute__((ext_vector_type(4)));

__device__ __forceinline__ ushortT f2bf(float f) {
    union { float f; unsigned int i; } v; v.f = f;
    unsigned int x = v.i;
    unsigned int r = (x + 0x7fffu + ((x >> 16) & 1u)) >> 16;  // RNE
    return (ushortT)r;
}
__device__ __forceinline__ float bf_lo(uintT w) {
    union { unsigned int i; float f; } v; v.i = w << 16; return v.f;
}
__device__ __forceinline__ float bf_hi(uintT w) {
    union { unsigned int i; float f; } v; v.i = w & 0xffff0000u; return v.f;
}

// ---- MFMA GEMM body + fused s,d epilogue; 2 row-tiles (32 rows) per wave ----
// Stages raw fp32 W into LDS directly in bf16 B-fragment order (inline pack).
template <int FIN, int FOUT, bool ABF16>
__device__ __forceinline__ void gemm_body(const void* __restrict__ A,
                                          const float* __restrict__ W,
                                          const float* __restrict__ ASrc,
                                          const float* __restrict__ ADst,
                                          ushortT* __restrict__ out,
                                          float* __restrict__ s_out_g,
                                          float* __restrict__ d_out_g,
                                          int nrows, int bid) {
    constexpr int KC = FIN / 32;
    constexpr int NT = FOUT / 16;
    constexpr int NTH = (FOUT / HEADS) / 16;  // nt tiles per head
    __shared__ uintT lW[FIN * FOUT / 2];      // 64 KB max
    int tid = threadIdx.x;
    constexpr int NQ = FIN * FOUT / 8;        // uint4 count
    for (int i = tid; i < NQ; i += 256) {
        int lane = i & 63, g = i >> 6;
        int kc = g % KC, nt = g / KC;
        int n = nt * 16 + (lane & 15);
        int kbase = kc * 32 + (lane >> 4) * 8;
        union { uint4 q; ushortT u[8]; } pk;
#pragma unroll
        for (int j = 0; j < 8; j++) pk.u[j] = f2bf(W[(kbase + j) * FOUT + n]);
        ((uint4*)lW)[i] = pk.q;
    }
    __syncthreads();

    int wave = tid >> 6, lane = tid & 63;
    long rowA = (long)bid * 128 + wave * 32;
    long rowB = rowA + 16;
    bool doA = rowA < nrows, doB = rowB < nrows;  // wave-uniform (nrows%16==0)
    if (!doA) return;
    int m = lane & 15, b = lane >> 4;

    v8s afA[KC], afB[KC];
    if (ABF16) {
        const ushortT* Ab = (const ushortT*)A;
#pragma unroll
        for (int kc = 0; kc < KC; kc++) {
            union { v8s v; uint4 q; } u;
            u.q = *(const uint4*)(Ab + (rowA + m) * FIN + kc * 32 + b * 8);
            afA[kc] = u.v;
            if (doB) {
                u.q = *(const uint4*)(Ab + (rowB + m) * FIN + kc * 32 + b * 8);
                afB[kc] = u.v;
            }
        }
    } else {
        const float* Af = (const float*)A;
#pragma unroll
        for (int kc = 0; kc < KC; kc++) {
            union { v8s v; ushortT u[8]; } u;
            const float* p = Af + (rowA + m) * FIN + kc * 32 + b * 8;
#pragma unroll
            for (int j = 0; j < 8; j++) u.u[j] = f2bf(p[j]);
            afA[kc] = u.v;
            if (doB) {
                const float* q = Af + (rowB + m) * FIN + kc * 32 + b * 8;
#pragma unroll
                for (int j = 0; j < 8; j++) u.u[j] = f2bf(q[j]);
                afB[kc] = u.v;
            }
        }
    }

    float spA[4] = {0,0,0,0}, dpA[4] = {0,0,0,0};
    float spB[4] = {0,0,0,0}, dpB[4] = {0,0,0,0};
    float skA[4], dkA[4], skB[4], dkB[4];
    const ushortT* lWs = (const ushortT*)lW;
#pragma unroll
    for (int nt = 0; nt < NT; nt++) {
        v4f cA = {0.f, 0.f, 0.f, 0.f}, cB = {0.f, 0.f, 0.f, 0.f};
#pragma unroll
        for (int kc = 0; kc < KC; kc++) {
            union { v8s v; uint4 q; } bu;
            bu.q = *(const uint4*)(lWs + ((nt * KC + kc) * 64 + lane) * 8);
            cA = __builtin_amdgcn_mfma_f32_16x16x32_bf16(afA[kc], bu.v, cA, 0, 0, 0);
            if (doB)
                cB = __builtin_amdgcn_mfma_f32_16x16x32_bf16(afB[kc], bu.v, cB, 0, 0, 0);
        }
        // C/D: col = lane&15, row = (lane>>4)*4 + reg   [measured m89/m91]
        int col = nt * 16 + m;
        float av = ASrc[col], dv = ADst[col];
        long rA = rowA + b * 4;
#pragma unroll
        for (int reg = 0; reg < 4; reg++) {
            out[(rA + reg) * FOUT + col] = f2bf(cA[reg]);
            spA[reg] += cA[reg] * av;
            dpA[reg] += cA[reg] * dv;
        }
        if (doB) {
            long rB = rowB + b * 4;
#pragma unroll
            for (int reg = 0; reg < 4; reg++) {
                out[(rB + reg) * FOUT + col] = f2bf(cB[reg]);
                spB[reg] += cB[reg] * av;
                dpB[reg] += cB[reg] * dv;
            }
        }
        if ((nt % NTH) == NTH - 1) {  // head boundary: reduce over 16 m-lanes
#pragma unroll
            for (int o = 1; o < 16; o <<= 1) {
#pragma unroll
                for (int reg = 0; reg < 4; reg++) {
                    spA[reg] += __shfl_xor(spA[reg], o, 64);
                    dpA[reg] += __shfl_xor(dpA[reg], o, 64);
                    spB[reg] += __shfl_xor(spB[reg], o, 64);
                    dpB[reg] += __shfl_xor(dpB[reg], o, 64);
                }
            }
            int hd = nt / NTH;
#pragma unroll
            for (int reg = 0; reg < 4; reg++) {
                if (m == hd) {
                    skA[reg] = spA[reg]; dkA[reg] = dpA[reg];
                    skB[reg] = spB[reg]; dkB[reg] = dpB[reg];
                }
                spA[reg] = 0.f; dpA[reg] = 0.f;
                spB[reg] = 0.f; dpB[reg] = 0.f;
            }
        }
    }
    if (m < HEADS) {
        long rA = rowA + b * 4;
#pragma unroll
        for (int reg = 0; reg < 4; reg++) {
            s_out_g[(rA + reg) * HEADS + m] = skA[reg];
            d_out_g[(rA + reg) * HEADS + m] = dkA[reg];
        }
        if (doB) {
            long rB = rowB + b * 4;
#pragma unroll
            for (int reg = 0; reg < 4; reg++) {
                s_out_g[(rB + reg) * HEADS + m] = skB[reg];
                d_out_g[(rB + reg) * HEADS + m] = dkB[reg];
            }
        }
    }
}

// ---- mega kernel: gemm1 + edge count (count also RECORDS each edge's rank,
// making the later scatter atomic-free; the atomic is hidden under gemm1) ----
__global__ __launch_bounds__(256) void k_mega1(
        const float* __restrict__ x, const float* __restrict__ W1,
        const float* __restrict__ asrc1, const float* __restrict__ adst1,
        ushortT* __restrict__ u_h, float* __restrict__ f_s, float* __restrict__ f_d,
        const int* __restrict__ ei, int* __restrict__ counts,
        int* __restrict__ rank) {
    if (blockIdx.x < GEMM_GRID) {
        gemm_body<IN_CH, F1, false>(x, W1, asrc1, adst1, u_h, f_s, f_d,
                                    N_NODES, blockIdx.x);
    } else {
        int e = (blockIdx.x - GEMM_GRID) * 256 + threadIdx.x;
        if (e < N_EDGES) {
            int dst = ei[N_EDGES + e];
            rank[e] = atomicAdd(&counts[dst], 1);
        }
    }
}

__global__ __launch_bounds__(256) void k_gemm2(
        const ushortT* __restrict__ A, const float* __restrict__ W2,
        const float* __restrict__ asrc2, const float* __restrict__ adst2,
        ushortT* __restrict__ u_h, float* __restrict__ f_s, float* __restrict__ f_d) {
    gemm_body<F1, F2, true>(A, W2, asrc2, adst2, u_h, f_s, f_d,
                            N_NODES, blockIdx.x);
}

// ---- 2-phase exclusive scan (consumers add bbase inline) ----
__global__ void k_scan1(const int* __restrict__ counts, int* __restrict__ offs,
                        int* __restrict__ bsum) {
    __shared__ int sh[SCAN_B];
    int b = blockIdx.x, t = threadIdx.x;
    int i = b * SCAN_B + t;
    int v = (i < N_NODES) ? counts[i] : 0;
    sh[t] = v;
    __syncthreads();
    for (int o = 1; o < SCAN_B; o <<= 1) {
        int add = (t >= o) ? sh[t - o] : 0;
        __syncthreads();
        sh[t] += add;
        __syncthreads();
    }
    if (i < N_NODES) offs[i] = sh[t] - v;  // block-local exclusive
    if (t == SCAN_B - 1) bsum[b] = sh[t];
}

__global__ void k_scan2(const int* __restrict__ bsum, int* __restrict__ bbase,
                        int* __restrict__ offs, const int* __restrict__ batch,
                        int* __restrict__ bounds) {
    __shared__ int sh[SCAN_B];
    int t = threadIdx.x;
    int v = (t < SCAN_NB) ? bsum[t] : 0;
    sh[t] = v;
    __syncthreads();
    for (int o = 1; o < SCAN_B; o <<= 1) {
        int add = (t >= o) ? sh[t - o] : 0;
        __syncthreads();
        sh[t] += add;
        __syncthreads();
    }
    if (t < SCAN_NB) bbase[t] = sh[t] - v;      // exclusive base per block
    if (t == SCAN_B - 1) offs[N_NODES] = sh[t]; // grand total (= N_EDGES)
    // fused: graph boundaries via binary search on sorted batch
    if (t <= N_GRAPHS) {
        int lo = 0, hi = N_NODES;
        while (lo < hi) {
            int mid = (lo + hi) >> 1;
            if (batch[mid] < t) lo = mid + 1; else hi = mid;
        }
        bounds[t] = lo;
    }
}

// ---- scatter: ATOMIC-FREE (rank precomputed during count) ----
__global__ void k_scatter(const int* __restrict__ ei, const int* __restrict__ offs,
                          const int* __restrict__ bbase, const int* __restrict__ rank,
                          int* __restrict__ csr_src) {
    int e = blockIdx.x * blockDim.x + threadIdx.x;
    if (e >= N_EDGES) return;
    int src = ei[e], dst = ei[N_EDGES + e];
    int pos = offs[dst] + bbase[dst >> 8] + rank[e];
    csr_src[pos] = src;
}

// ---- fused segment-softmax + aggregation: one node per wave, NO barriers ----
// (r9/r12 loop body — measured best: unroll 4, VGPR 28, WPB=4.) Self-loop
// implicit in registers; CSR offsets finalized inline via bbase fixup.
template <int H, int C, int VEC, bool OUT_BF16, int WPB, int CHUNK>
__global__ __launch_bounds__(64 * WPB) void k_agg(
        const ushortT* __restrict__ hb, const float* __restrict__ s,
        const float* __restrict__ d, const int* __restrict__ offs,
        const int* __restrict__ bbase, const int* __restrict__ csr_src,
        const float* __restrict__ bias, void* __restrict__ xout) {
    static_assert(H == 4, "H=4 assumed");
    constexpr int F = H * C;
    constexpr int TPN = F / VEC;
    static_assert(TPN == 64, "one wave per node");
    __shared__ int lsrc[WPB][CHUNK];
    __shared__ float lex[WPB][CHUNK * H];
    int wv = threadIdx.x >> 6;
    int n = blockIdx.x * WPB + wv;
    if (n >= N_NODES) return;
    int t = threadIdx.x & 63;
    int h = t / (C / VEC);
    int beg = offs[n] + bbase[n >> 8];
    int np1 = n + 1;
    int end = (np1 < N_NODES) ? offs[np1] + bbase[np1 >> 8] : offs[N_NODES];
    float4 dn = *(const float4*)(d + n * 4);

    const uint2* hb2 = (const uint2*)hb;
    const uintT* hb1 = (const uintT*)hb;

    // implicit self-loop: init sumex/acc from own s,d,h (outside the hot loop)
    float4 svn = *(const float4*)(s + n * 4);
    float ssel = (h == 0) ? svn.x : (h == 1) ? svn.y : (h == 2) ? svn.z : svn.w;
    float dsel = (h == 0) ? dn.x : (h == 1) ? dn.y : (h == 2) ? dn.z : dn.w;
    float es = ssel + dsel; es = es > 0.f ? es : 0.2f * es;
    float exs = __expf(es);
    float sumex = exs;
    float acc[VEC];
    if (VEC == 4) {
        uint2 w = hb2[(long)n * TPN + t];
        acc[0] = exs * bf_lo(w.x); acc[1] = exs * bf_hi(w.x);
        acc[2] = exs * bf_lo(w.y); acc[3] = exs * bf_hi(w.y);
    } else {
        uintT w = hb1[(long)n * TPN + t];
        acc[0] = exs * bf_lo(w); acc[1] = exs * bf_hi(w);
    }

    for (int base = beg; base < end; base += CHUNK) {
        int cnt = min(CHUNK, end - base);
        // phase 1: stage src ids + per-head exp into this wave's LDS slice
        for (int i = t; i < cnt; i += 64) {
            int sn = csr_src[base + i];
            lsrc[wv][i] = sn;
            float4 sv = *(const float4*)(s + sn * 4);
            float e0 = sv.x + dn.x; e0 = e0 > 0.f ? e0 : 0.2f * e0;
            float e1 = sv.y + dn.y; e1 = e1 > 0.f ? e1 : 0.2f * e1;
            float e2 = sv.z + dn.z; e2 = e2 > 0.f ? e2 : 0.2f * e2;
            float e3 = sv.w + dn.w; e3 = e3 > 0.f ? e3 : 0.2f * e3;
            float4 exv = { __expf(e0), __expf(e1), __expf(e2), __expf(e3) };
            *(float4*)&lex[wv][i * 4] = exv;
        }
        // intra-wave LDS write->read ordering (no block barrier needed)
        asm volatile("s_waitcnt lgkmcnt(0)" ::: "memory");
        // phase 2: accumulate (unroll 4 = measured best; VGPR stays ~28)
#pragma unroll 4
        for (int i = 0; i < cnt; i++) {
            float ex = lex[wv][i * H + h];
            int sn = lsrc[wv][i];
            sumex += ex;
            if (VEC == 4) {
                uint2 w = hb2[(long)sn * TPN + t];
                acc[0] += ex * bf_lo(w.x);
                acc[1] += ex * bf_hi(w.x);
                acc[2] += ex * bf_lo(w.y);
                acc[3] += ex * bf_hi(w.y);
            } else {
                uintT w = hb1[(long)sn * TPN + t];
                acc[0] += ex * bf_lo(w);
                acc[1] += ex * bf_hi(w);
            }
        }
        asm volatile("" ::: "memory");
    }
    float inv = 1.f / (sumex + 1e-16f);
    float o[VEC];
#pragma unroll
    for (int j = 0; j < VEC; j++)
        o[j] = fmaxf(acc[j] * inv + bias[t * VEC + j], 0.f);
    if (OUT_BF16) {
        if (VEC == 4) {
            uint2 pk;
            pk.x = (uintT)f2bf(o[0]) | ((uintT)f2bf(o[1]) << 16);
            pk.y = (uintT)f2bf(o[2]) | ((uintT)f2bf(o[3]) << 16);
            ((uint2*)xout)[(long)n * TPN + t] = pk;
        } else {
            uintT pk = (uintT)f2bf(o[0]) | ((uintT)f2bf(o[1]) << 16);
            ((uintT*)xout)[(long)n * TPN + t] = pk;
        }
    } else {
        float* xo = (float*)xout;
#pragma unroll
        for (int j = 0; j < VEC; j++) xo[(long)n * F + t * VEC + j] = o[j];
    }
}

// ---- fused pool+head: one block per graph; sum slice, dot Wout, softmax ----
__global__ __launch_bounds__(256) void k_pool_head(
        const ushortT* __restrict__ x2, const int* __restrict__ bounds,
        const float* __restrict__ Wout, const float* __restrict__ bout,
        float* __restrict__ out) {
    __shared__ float r0[256], r1[256];
    int g = blockIdx.x, t = threadIdx.x;
    int n0 = bounds[g], n1 = bounds[g + 1];
    int feat = t & 127, half = t >> 7;  // 2 rows in flight per iteration
    float acc = 0.f;
    for (int n = n0 + half; n < n1; n += 2)
        acc += bf_lo((uintT)x2[(long)n * F2 + feat]);
    float cnt = fmaxf((float)(n1 - n0), 1.0f);
    float p = acc / cnt;
    r0[t] = p * Wout[feat * 2 + 0];
    r1[t] = p * Wout[feat * 2 + 1];
    __syncthreads();
    for (int o = 128; o > 0; o >>= 1) {
        if (t < o) { r0[t] += r0[t + o]; r1[t] += r1[t + o]; }
        __syncthreads();
    }
    if (t == 0) {
        float l0 = r0[0] + bout[0];
        float l1 = r1[0] + bout[1];
        float m = fmaxf(l0, l1);
        float e0 = __expf(l0 - m), e1 = __expf(l1 - m);
        float inv = 1.f / (e0 + e1);
        out[g * 2 + 0] = e0 * inv;
        out[g * 2 + 1] = e1 * inv;
    }
}

extern "C" void kernel_launch(void* const* d_in, const int* in_sizes, int n_in,
                              void* d_out, int out_size, void* d_ws, size_t ws_size,
                              hipStream_t stream) {
    const float* x     = (const float*)d_in[0];
    const int*   ei    = (const int*)d_in[1];
    const int*   batch = (const int*)d_in[2];
    const float* W1    = (const float*)d_in[3];
    const float* asrc1 = (const float*)d_in[4];
    const float* adst1 = (const float*)d_in[5];
    const float* b1    = (const float*)d_in[6];
    const float* W2    = (const float*)d_in[7];
    const float* asrc2 = (const float*)d_in[8];
    const float* adst2 = (const float*)d_in[9];
    const float* b2    = (const float*)d_in[10];
    const float* Wout  = (const float*)d_in[11];
    const float* bout  = (const float*)d_in[12];

    char* ws = (char*)d_ws;
    size_t off = 0;
    auto alloc = [&](size_t bytes) -> void* {
        void* p = ws + off;
        off += (bytes + 255) / 256 * 256;
        return p;
    };
    ushortT* u_h   = (ushortT*)alloc(sizeof(ushortT) * (size_t)N_NODES * F1);
    ushortT* u_x1  = (ushortT*)alloc(sizeof(ushortT) * (size_t)N_NODES * F1);
    ushortT* u_x2  = (ushortT*)alloc(sizeof(ushortT) * (size_t)N_NODES * F2);
    float*   f_s   = (float*)alloc(sizeof(float) * (size_t)N_NODES * HEADS);
    float*   f_d   = (float*)alloc(sizeof(float) * (size_t)N_NODES * HEADS);
    int*     i_cnt = (int*)alloc(sizeof(int) * (size_t)N_NODES);
    int*     i_off = (int*)alloc(sizeof(int) * (size_t)(N_NODES + 1));
    int*     i_rnk = (int*)alloc(sizeof(int) * (size_t)N_EDGES);
    int*     i_csr = (int*)alloc(sizeof(int) * (size_t)N_EDGES);
    int*     i_bnd = (int*)alloc(sizeof(int) * (size_t)(N_GRAPHS + 1));
    int*     i_bs  = (int*)alloc(sizeof(int) * SCAN_NB);
    int*     i_bb  = (int*)alloc(sizeof(int) * SCAN_NB);
    (void)ws_size; (void)in_sizes; (void)n_in; (void)out_size;

    hipMemsetAsync(i_cnt, 0, sizeof(int) * N_NODES, stream);

    // mega: gemm1 (inline W-pack, fused s/d epilogue) + CSR count-with-rank
    k_mega1<<<GEMM_GRID + COUNT_GRID, 256, 0, stream>>>(
        x, W1, asrc1, adst1, u_h, f_s, f_d, ei, i_cnt, i_rnk);

    // 2-phase scan (+bounds); atomic-free scatter using precomputed ranks
    k_scan1<<<SCAN_NB, SCAN_B, 0, stream>>>(i_cnt, i_off, i_bs);
    k_scan2<<<1, SCAN_B, 0, stream>>>(i_bs, i_bb, i_off, batch, i_bnd);
    k_scatter<<<COUNT_GRID, 256, 0, stream>>>(ei, i_off, i_bb, i_rnk, i_csr);

    int agg_grid = (N_NODES + 3) / 4;  // 1 node per wave, 4 waves per block

    // Layer 1 aggregation
    k_agg<HEADS, HID, 4, true, 4, 128><<<agg_grid, 256, 0, stream>>>(
        u_h, f_s, f_d, i_off, i_bb, i_csr, b1, u_x1);

    // Layer 2
    k_gemm2<<<GEMM_GRID, 256, 0, stream>>>(u_x1, W2, asrc2, adst2, u_h, f_s, f_d);
    k_agg<HEADS, OUT_CH, 2, true, 4, 128><<<agg_grid, 256, 0, stream>>>(
        u_h, f_s, f_d, i_off, i_bb, i_csr, b2, u_x2);

    // Fused pool + head (no atomics: batch sorted -> contiguous ranges)
    k_pool_head<<<N_GRAPHS, 256, 0, stream>>>(u_x2, i_bnd, Wout, bout, (float*)d_out);
}

// Round 18
// 294.160 us; speedup vs baseline: 1.2806x; 1.2806x over previous
//
#include <hip/hip_runtime.h>
#include <hip/hip_bf16.h>

#define N_NODES 50000
#define N_EDGES 800000
#define N_GRAPHS 64
#define HEADS 4
#define IN_CH 128
#define HID 64
#define F1 256  // HEADS*HID
#define OUT_CH 32
#define F2 128  // HEADS*OUT_CH
#define POOL_SPLITS 16
#define SCAN_B 256
#define SCAN_NB ((N_NODES + SCAN_B - 1) / SCAN_B)  // 196
#define GEMM_GRID ((N_NODES + 127) / 128)          // 391 (32 rows/wave)
#define COUNT_GRID ((N_EDGES + 255) / 256)         // 3125

typedef unsigned short ushortT;
typedef unsigned int uintT;
typedef short v8s __attribute__((ext_vector_type(8)));
typedef float v4f __attribute__((ext_vector_type(4)));

__device__ __forceinline__ ushortT f2bf(float f) {
    union { float f; unsigned int i; } v; v.f = f;
    unsigned int x = v.i;
    unsigned int r = (x + 0x7fffu + ((x >> 16) & 1u)) >> 16;  // RNE
    return (ushortT)r;
}
__device__ __forceinline__ float bf_lo(uintT w) {
    union { unsigned int i; float f; } v; v.i = w << 16; return v.f;
}
__device__ __forceinline__ float bf_hi(uintT w) {
    union { unsigned int i; float f; } v; v.i = w & 0xffff0000u; return v.f;
}

// ---- MFMA GEMM body + fused s,d epilogue; 2 row-tiles (32 rows) per wave ----
// Stages raw fp32 W into LDS directly in bf16 B-fragment order (inline pack).
template <int FIN, int FOUT, bool ABF16>
__device__ __forceinline__ void gemm_body(const void* __restrict__ A,
                                          const float* __restrict__ W,
                                          const float* __restrict__ ASrc,
                                          const float* __restrict__ ADst,
                                          ushortT* __restrict__ out,
                                          float* __restrict__ s_out_g,
                                          float* __restrict__ d_out_g,
                                          int nrows, int bid) {
    constexpr int KC = FIN / 32;
    constexpr int NT = FOUT / 16;
    constexpr int NTH = (FOUT / HEADS) / 16;  // nt tiles per head
    __shared__ uintT lW[FIN * FOUT / 2];      // 64 KB max
    int tid = threadIdx.x;
    constexpr int NQ = FIN * FOUT / 8;        // uint4 count
    for (int i = tid; i < NQ; i += 256) {
        int lane = i & 63, g = i >> 6;
        int kc = g % KC, nt = g / KC;
        int n = nt * 16 + (lane & 15);
        int kbase = kc * 32 + (lane >> 4) * 8;
        union { uint4 q; ushortT u[8]; } pk;
#pragma unroll
        for (int j = 0; j < 8; j++) pk.u[j] = f2bf(W[(kbase + j) * FOUT + n]);
        ((uint4*)lW)[i] = pk.q;
    }
    __syncthreads();

    int wave = tid >> 6, lane = tid & 63;
    long rowA = (long)bid * 128 + wave * 32;
    long rowB = rowA + 16;
    bool doA = rowA < nrows, doB = rowB < nrows;  // wave-uniform (nrows%16==0)
    if (!doA) return;
    int m = lane & 15, b = lane >> 4;

    v8s afA[KC], afB[KC];
    if (ABF16) {
        const ushortT* Ab = (const ushortT*)A;
#pragma unroll
        for (int kc = 0; kc < KC; kc++) {
            union { v8s v; uint4 q; } u;
            u.q = *(const uint4*)(Ab + (rowA + m) * FIN + kc * 32 + b * 8);
            afA[kc] = u.v;
            if (doB) {
                u.q = *(const uint4*)(Ab + (rowB + m) * FIN + kc * 32 + b * 8);
                afB[kc] = u.v;
            }
        }
    } else {
        const float* Af = (const float*)A;
#pragma unroll
        for (int kc = 0; kc < KC; kc++) {
            union { v8s v; ushortT u[8]; } u;
            const float* p = Af + (rowA + m) * FIN + kc * 32 + b * 8;
#pragma unroll
            for (int j = 0; j < 8; j++) u.u[j] = f2bf(p[j]);
            afA[kc] = u.v;
            if (doB) {
                const float* q = Af + (rowB + m) * FIN + kc * 32 + b * 8;
#pragma unroll
                for (int j = 0; j < 8; j++) u.u[j] = f2bf(q[j]);
                afB[kc] = u.v;
            }
        }
    }

    float spA[4] = {0,0,0,0}, dpA[4] = {0,0,0,0};
    float spB[4] = {0,0,0,0}, dpB[4] = {0,0,0,0};
    float skA[4], dkA[4], skB[4], dkB[4];
    const ushortT* lWs = (const ushortT*)lW;
#pragma unroll
    for (int nt = 0; nt < NT; nt++) {
        v4f cA = {0.f, 0.f, 0.f, 0.f}, cB = {0.f, 0.f, 0.f, 0.f};
#pragma unroll
        for (int kc = 0; kc < KC; kc++) {
            union { v8s v; uint4 q; } bu;
            bu.q = *(const uint4*)(lWs + ((nt * KC + kc) * 64 + lane) * 8);
            cA = __builtin_amdgcn_mfma_f32_16x16x32_bf16(afA[kc], bu.v, cA, 0, 0, 0);
            if (doB)
                cB = __builtin_amdgcn_mfma_f32_16x16x32_bf16(afB[kc], bu.v, cB, 0, 0, 0);
        }
        // C/D: col = lane&15, row = (lane>>4)*4 + reg   [measured m89/m91]
        int col = nt * 16 + m;
        float av = ASrc[col], dv = ADst[col];
        long rA = rowA + b * 4;
#pragma unroll
        for (int reg = 0; reg < 4; reg++) {
            out[(rA + reg) * FOUT + col] = f2bf(cA[reg]);
            spA[reg] += cA[reg] * av;
            dpA[reg] += cA[reg] * dv;
        }
        if (doB) {
            long rB = rowB + b * 4;
#pragma unroll
            for (int reg = 0; reg < 4; reg++) {
                out[(rB + reg) * FOUT + col] = f2bf(cB[reg]);
                spB[reg] += cB[reg] * av;
                dpB[reg] += cB[reg] * dv;
            }
        }
        if ((nt % NTH) == NTH - 1) {  // head boundary: reduce over 16 m-lanes
#pragma unroll
            for (int o = 1; o < 16; o <<= 1) {
#pragma unroll
                for (int reg = 0; reg < 4; reg++) {
                    spA[reg] += __shfl_xor(spA[reg], o, 64);
                    dpA[reg] += __shfl_xor(dpA[reg], o, 64);
                    spB[reg] += __shfl_xor(spB[reg], o, 64);
                    dpB[reg] += __shfl_xor(dpB[reg], o, 64);
                }
            }
            int hd = nt / NTH;
#pragma unroll
            for (int reg = 0; reg < 4; reg++) {
                if (m == hd) {
                    skA[reg] = spA[reg]; dkA[reg] = dpA[reg];
                    skB[reg] = spB[reg]; dkB[reg] = dpB[reg];
                }
                spA[reg] = 0.f; dpA[reg] = 0.f;
                spB[reg] = 0.f; dpB[reg] = 0.f;
            }
        }
    }
    if (m < HEADS) {
        long rA = rowA + b * 4;
#pragma unroll
        for (int reg = 0; reg < 4; reg++) {
            s_out_g[(rA + reg) * HEADS + m] = skA[reg];
            d_out_g[(rA + reg) * HEADS + m] = dkA[reg];
        }
        if (doB) {
            long rB = rowB + b * 4;
#pragma unroll
            for (int reg = 0; reg < 4; reg++) {
                s_out_g[(rB + reg) * HEADS + m] = skB[reg];
                d_out_g[(rB + reg) * HEADS + m] = dkB[reg];
            }
        }
    }
}

// ---- mega kernel: gemm1 + edge count (count also RECORDS each edge's rank,
// making the later scatter atomic-free; the atomic is hidden under gemm1) ----
__global__ __launch_bounds__(256) void k_mega1(
        const float* __restrict__ x, const float* __restrict__ W1,
        const float* __restrict__ asrc1, const float* __restrict__ adst1,
        ushortT* __restrict__ u_h, float* __restrict__ f_s, float* __restrict__ f_d,
        const int* __restrict__ ei, int* __restrict__ counts,
        int* __restrict__ rank) {
    if (blockIdx.x < GEMM_GRID) {
        gemm_body<IN_CH, F1, false>(x, W1, asrc1, adst1, u_h, f_s, f_d,
                                    N_NODES, blockIdx.x);
    } else {
        int e = (blockIdx.x - GEMM_GRID) * 256 + threadIdx.x;
        if (e < N_EDGES) {
            int dst = ei[N_EDGES + e];
            rank[e] = atomicAdd(&counts[dst], 1);
        }
    }
}

__global__ __launch_bounds__(256) void k_gemm2(
        const ushortT* __restrict__ A, const float* __restrict__ W2,
        const float* __restrict__ asrc2, const float* __restrict__ adst2,
        ushortT* __restrict__ u_h, float* __restrict__ f_s, float* __restrict__ f_d) {
    gemm_body<F1, F2, true>(A, W2, asrc2, adst2, u_h, f_s, f_d,
                            N_NODES, blockIdx.x);
}

// ---- 2-phase exclusive scan (consumers add bbase inline) ----
__global__ void k_scan1(const int* __restrict__ counts, int* __restrict__ offs,
                        int* __restrict__ bsum) {
    __shared__ int sh[SCAN_B];
    int b = blockIdx.x, t = threadIdx.x;
    int i = b * SCAN_B + t;
    int v = (i < N_NODES) ? counts[i] : 0;
    sh[t] = v;
    __syncthreads();
    for (int o = 1; o < SCAN_B; o <<= 1) {
        int add = (t >= o) ? sh[t - o] : 0;
        __syncthreads();
        sh[t] += add;
        __syncthreads();
    }
    if (i < N_NODES) offs[i] = sh[t] - v;  // block-local exclusive
    if (t == SCAN_B - 1) bsum[b] = sh[t];
}

__global__ void k_scan2(const int* __restrict__ bsum, int* __restrict__ bbase,
                        int* __restrict__ offs, const int* __restrict__ batch,
                        int* __restrict__ bounds) {
    __shared__ int sh[SCAN_B];
    int t = threadIdx.x;
    int v = (t < SCAN_NB) ? bsum[t] : 0;
    sh[t] = v;
    __syncthreads();
    for (int o = 1; o < SCAN_B; o <<= 1) {
        int add = (t >= o) ? sh[t - o] : 0;
        __syncthreads();
        sh[t] += add;
        __syncthreads();
    }
    if (t < SCAN_NB) bbase[t] = sh[t] - v;      // exclusive base per block
    if (t == SCAN_B - 1) offs[N_NODES] = sh[t]; // grand total (= N_EDGES)
    // fused: graph boundaries via binary search on sorted batch
    if (t <= N_GRAPHS) {
        int lo = 0, hi = N_NODES;
        while (lo < hi) {
            int mid = (lo + hi) >> 1;
            if (batch[mid] < t) lo = mid + 1; else hi = mid;
        }
        bounds[t] = lo;
    }
}

// ---- scatter: ATOMIC-FREE (rank precomputed during count) ----
__global__ void k_scatter(const int* __restrict__ ei, const int* __restrict__ offs,
                          const int* __restrict__ bbase, const int* __restrict__ rank,
                          int* __restrict__ csr_src) {
    int e = blockIdx.x * blockDim.x + threadIdx.x;
    if (e >= N_EDGES) return;
    int src = ei[e], dst = ei[N_EDGES + e];
    int pos = offs[dst] + bbase[dst >> 8] + rank[e];
    csr_src[pos] = src;
}

// ---- fused segment-softmax + aggregation: one node per wave, NO barriers ----
// (r9/r12 loop body — measured best: unroll 4, VGPR 28, WPB=4.) Self-loop
// implicit in registers; CSR offsets finalized inline via bbase fixup.
template <int H, int C, int VEC, bool OUT_BF16, int WPB, int CHUNK>
__global__ __launch_bounds__(64 * WPB) void k_agg(
        const ushortT* __restrict__ hb, const float* __restrict__ s,
        const float* __restrict__ d, const int* __restrict__ offs,
        const int* __restrict__ bbase, const int* __restrict__ csr_src,
        const float* __restrict__ bias, void* __restrict__ xout) {
    static_assert(H == 4, "H=4 assumed");
    constexpr int F = H * C;
    constexpr int TPN = F / VEC;
    static_assert(TPN == 64, "one wave per node");
    __shared__ int lsrc[WPB][CHUNK];
    __shared__ float lex[WPB][CHUNK * H];
    int wv = threadIdx.x >> 6;
    int n = blockIdx.x * WPB + wv;
    if (n >= N_NODES) return;
    int t = threadIdx.x & 63;
    int h = t / (C / VEC);
    int beg = offs[n] + bbase[n >> 8];
    int np1 = n + 1;
    int end = (np1 < N_NODES) ? offs[np1] + bbase[np1 >> 8] : offs[N_NODES];
    float4 dn = *(const float4*)(d + n * 4);

    const uint2* hb2 = (const uint2*)hb;
    const uintT* hb1 = (const uintT*)hb;

    // implicit self-loop: init sumex/acc from own s,d,h (outside the hot loop)
    float4 svn = *(const float4*)(s + n * 4);
    float ssel = (h == 0) ? svn.x : (h == 1) ? svn.y : (h == 2) ? svn.z : svn.w;
    float dsel = (h == 0) ? dn.x : (h == 1) ? dn.y : (h == 2) ? dn.z : dn.w;
    float es = ssel + dsel; es = es > 0.f ? es : 0.2f * es;
    float exs = __expf(es);
    float sumex = exs;
    float acc[VEC];
    if (VEC == 4) {
        uint2 w = hb2[(long)n * TPN + t];
        acc[0] = exs * bf_lo(w.x); acc[1] = exs * bf_hi(w.x);
        acc[2] = exs * bf_lo(w.y); acc[3] = exs * bf_hi(w.y);
    } else {
        uintT w = hb1[(long)n * TPN + t];
        acc[0] = exs * bf_lo(w); acc[1] = exs * bf_hi(w);
    }

    for (int base = beg; base < end; base += CHUNK) {
        int cnt = min(CHUNK, end - base);
        // phase 1: stage src ids + per-head exp into this wave's LDS slice
        for (int i = t; i < cnt; i += 64) {
            int sn = csr_src[base + i];
            lsrc[wv][i] = sn;
            float4 sv = *(const float4*)(s + sn * 4);
            float e0 = sv.x + dn.x; e0 = e0 > 0.f ? e0 : 0.2f * e0;
            float e1 = sv.y + dn.y; e1 = e1 > 0.f ? e1 : 0.2f * e1;
            float e2 = sv.z + dn.z; e2 = e2 > 0.f ? e2 : 0.2f * e2;
            float e3 = sv.w + dn.w; e3 = e3 > 0.f ? e3 : 0.2f * e3;
            float4 exv = { __expf(e0), __expf(e1), __expf(e2), __expf(e3) };
            *(float4*)&lex[wv][i * 4] = exv;
        }
        // intra-wave LDS write->read ordering (no block barrier needed)
        asm volatile("s_waitcnt lgkmcnt(0)" ::: "memory");
        // phase 2: accumulate (unroll 4 = measured best; VGPR stays ~28)
#pragma unroll 4
        for (int i = 0; i < cnt; i++) {
            float ex = lex[wv][i * H + h];
            int sn = lsrc[wv][i];
            sumex += ex;
            if (VEC == 4) {
                uint2 w = hb2[(long)sn * TPN + t];
                acc[0] += ex * bf_lo(w.x);
                acc[1] += ex * bf_hi(w.x);
                acc[2] += ex * bf_lo(w.y);
                acc[3] += ex * bf_hi(w.y);
            } else {
                uintT w = hb1[(long)sn * TPN + t];
                acc[0] += ex * bf_lo(w);
                acc[1] += ex * bf_hi(w);
            }
        }
        asm volatile("" ::: "memory");
    }
    float inv = 1.f / (sumex + 1e-16f);
    float o[VEC];
#pragma unroll
    for (int j = 0; j < VEC; j++)
        o[j] = fmaxf(acc[j] * inv + bias[t * VEC + j], 0.f);
    if (OUT_BF16) {
        if (VEC == 4) {
            uint2 pk;
            pk.x = (uintT)f2bf(o[0]) | ((uintT)f2bf(o[1]) << 16);
            pk.y = (uintT)f2bf(o[2]) | ((uintT)f2bf(o[3]) << 16);
            ((uint2*)xout)[(long)n * TPN + t] = pk;
        } else {
            uintT pk = (uintT)f2bf(o[0]) | ((uintT)f2bf(o[1]) << 16);
            ((uintT*)xout)[(long)n * TPN + t] = pk;
        }
    } else {
        float* xo = (float*)xout;
#pragma unroll
        for (int j = 0; j < VEC; j++) xo[(long)n * F + t * VEC + j] = o[j];
    }
}

// ---- pool partials over bf16 x2: block (g,s) sums a contiguous slice ----
// (r16 form — 1024 blocks keeps the machine full; r17's 64-block fusion was a
// 16x-parallelism regression, 106us.)
__global__ void k_pool_partial(const ushortT* __restrict__ x2, const int* __restrict__ bounds,
                               float* __restrict__ partial) {
    int g = blockIdx.x, s = blockIdx.y;
    int t = threadIdx.x;  // F2 threads
    int n0 = bounds[g], n1 = bounds[g + 1];
    int len = n1 - n0;
    int a = n0 + (int)((long)len * s / POOL_SPLITS);
    int b = n0 + (int)((long)len * (s + 1) / POOL_SPLITS);
    float acc = 0.f;
    for (int n = a; n < b; n++) acc += bf_lo((uintT)x2[(long)n * F2 + t]);
    partial[((long)g * POOL_SPLITS + s) * F2 + t] = acc;
}

// ---- head: block per graph — reduce partials, mean, logits, softmax ----
__global__ void k_head(const float* __restrict__ partial, const int* __restrict__ bounds,
                       const float* __restrict__ Wout, const float* __restrict__ bout,
                       float* __restrict__ out) {
    __shared__ float red0[F2], red1[F2];
    int g = blockIdx.x;
    int t = threadIdx.x;
    int cntN = bounds[g + 1] - bounds[g];
    float cnt = fmaxf((float)cntN, 1.0f);
    float sum = 0.f;
    for (int s = 0; s < POOL_SPLITS; s++)
        sum += partial[((long)g * POOL_SPLITS + s) * F2 + t];
    float p = sum / cnt;
    red0[t] = p * Wout[t * 2 + 0];
    red1[t] = p * Wout[t * 2 + 1];
    __syncthreads();
    for (int off = F2 / 2; off > 0; off >>= 1) {
        if (t < off) { red0[t] += red0[t + off]; red1[t] += red1[t + off]; }
        __syncthreads();
    }
    if (t == 0) {
        float l0 = red0[0] + bout[0];
        float l1 = red1[0] + bout[1];
        float m = fmaxf(l0, l1);
        float e0 = __expf(l0 - m), e1 = __expf(l1 - m);
        float inv = 1.f / (e0 + e1);
        out[g * 2 + 0] = e0 * inv;
        out[g * 2 + 1] = e1 * inv;
    }
}

extern "C" void kernel_launch(void* const* d_in, const int* in_sizes, int n_in,
                              void* d_out, int out_size, void* d_ws, size_t ws_size,
                              hipStream_t stream) {
    const float* x     = (const float*)d_in[0];
    const int*   ei    = (const int*)d_in[1];
    const int*   batch = (const int*)d_in[2];
    const float* W1    = (const float*)d_in[3];
    const float* asrc1 = (const float*)d_in[4];
    const float* adst1 = (const float*)d_in[5];
    const float* b1    = (const float*)d_in[6];
    const float* W2    = (const float*)d_in[7];
    const float* asrc2 = (const float*)d_in[8];
    const float* adst2 = (const float*)d_in[9];
    const float* b2    = (const float*)d_in[10];
    const float* Wout  = (const float*)d_in[11];
    const float* bout  = (const float*)d_in[12];

    char* ws = (char*)d_ws;
    size_t off = 0;
    auto alloc = [&](size_t bytes) -> void* {
        void* p = ws + off;
        off += (bytes + 255) / 256 * 256;
        return p;
    };
    ushortT* u_h   = (ushortT*)alloc(sizeof(ushortT) * (size_t)N_NODES * F1);
    ushortT* u_x1  = (ushortT*)alloc(sizeof(ushortT) * (size_t)N_NODES * F1);
    ushortT* u_x2  = (ushortT*)alloc(sizeof(ushortT) * (size_t)N_NODES * F2);
    float*   f_s   = (float*)alloc(sizeof(float) * (size_t)N_NODES * HEADS);
    float*   f_d   = (float*)alloc(sizeof(float) * (size_t)N_NODES * HEADS);
    int*     i_cnt = (int*)alloc(sizeof(int) * (size_t)N_NODES);
    int*     i_off = (int*)alloc(sizeof(int) * (size_t)(N_NODES + 1));
    int*     i_rnk = (int*)alloc(sizeof(int) * (size_t)N_EDGES);
    int*     i_csr = (int*)alloc(sizeof(int) * (size_t)N_EDGES);
    int*     i_bnd = (int*)alloc(sizeof(int) * (size_t)(N_GRAPHS + 1));
    int*     i_bs  = (int*)alloc(sizeof(int) * SCAN_NB);
    int*     i_bb  = (int*)alloc(sizeof(int) * SCAN_NB);
    float*   f_prt = (float*)alloc(sizeof(float) * (size_t)N_GRAPHS * POOL_SPLITS * F2);
    (void)ws_size; (void)in_sizes; (void)n_in; (void)out_size;

    hipMemsetAsync(i_cnt, 0, sizeof(int) * N_NODES, stream);

    // mega: gemm1 (inline W-pack, fused s/d epilogue) + CSR count-with-rank
    k_mega1<<<GEMM_GRID + COUNT_GRID, 256, 0, stream>>>(
        x, W1, asrc1, adst1, u_h, f_s, f_d, ei, i_cnt, i_rnk);

    // 2-phase scan (+bounds); atomic-free scatter using precomputed ranks
    k_scan1<<<SCAN_NB, SCAN_B, 0, stream>>>(i_cnt, i_off, i_bs);
    k_scan2<<<1, SCAN_B, 0, stream>>>(i_bs, i_bb, i_off, batch, i_bnd);
    k_scatter<<<COUNT_GRID, 256, 0, stream>>>(ei, i_off, i_bb, i_rnk, i_csr);

    int agg_grid = (N_NODES + 3) / 4;  // 1 node per wave, 4 waves per block

    // Layer 1 aggregation
    k_agg<HEADS, HID, 4, true, 4, 128><<<agg_grid, 256, 0, stream>>>(
        u_h, f_s, f_d, i_off, i_bb, i_csr, b1, u_x1);

    // Layer 2
    k_gemm2<<<GEMM_GRID, 256, 0, stream>>>(u_x1, W2, asrc2, adst2, u_h, f_s, f_d);
    k_agg<HEADS, OUT_CH, 2, true, 4, 128><<<agg_grid, 256, 0, stream>>>(
        u_h, f_s, f_d, i_off, i_bb, i_csr, b2, u_x2);

    // Pool (1024 blocks, machine-filling) + tiny head
    dim3 pgrid(N_GRAPHS, POOL_SPLITS);
    k_pool_partial<<<pgrid, F2, 0, stream>>>(u_x2, i_bnd, f_prt);
    k_head<<<N_GRAPHS, F2, 0, stream>>>(f_prt, i_bnd, Wout, bout, (float*)d_out);
}